// Round 2
// baseline (222.124 us; speedup 1.0000x reference)
//
#include <hip/hip_runtime.h>

// YOLO-v1 loss forward, S=7, B=2, C=20, bs=16384.
// Memory-bound streaming reduction: 193 MB in -> 4 B out. Floor ~31 us @ 6.3 TB/s.
// R2: coalesced float4 global loads staged through LDS (R1's per-lane stride-120B
// loads serialized in the TA at ~2 TB/s).

#define SS 7
#define CELL_STRIDE 30          // 5*B + C floats per cell
#define CELLS_PER_BLOCK 256
#define FLOATS_PER_BLOCK (CELLS_PER_BLOCK * CELL_STRIDE)   // 7680
#define VEC4_PER_BLOCK (FLOATS_PER_BLOCK / 4)              // 1920

__global__ void yolo_zero_out(float* out) {
    if (threadIdx.x == 0) out[0] = 0.0f;
}

__global__ __launch_bounds__(256) void yolo_loss_kernel(
    const float* __restrict__ preds,
    const float* __restrict__ labels,
    float* __restrict__ out,
    float inv_bs)
{
    __shared__ float sh[FLOATS_PER_BLOCK];   // 30720 B -> ~5 blocks/CU

    const int tid = threadIdx.x;
    const size_t blockFloatBase = (size_t)blockIdx.x * FLOATS_PER_BLOCK;

    // ---- phase 1: stage preds slab (coalesced float4), read my cell to regs ----
    {
        const float4* g = reinterpret_cast<const float4*>(preds + blockFloatBase);
        float4* s4 = reinterpret_cast<float4*>(sh);
        #pragma unroll
        for (int k = 0; k < 8; ++k) {
            const int i = tid + k * 256;
            if (i < VEC4_PER_BLOCK) s4[i] = g[i];
        }
    }
    __syncthreads();

    float pv[CELL_STRIDE];
    {
        const float* myp = sh + tid * CELL_STRIDE;
        #pragma unroll
        for (int k = 0; k < 15; ++k) {
            float2 t = *reinterpret_cast<const float2*>(myp + 2 * k);
            pv[2 * k] = t.x; pv[2 * k + 1] = t.y;
        }
    }
    __syncthreads();

    // ---- phase 2: stage labels slab into the same LDS buffer ----
    {
        const float4* g = reinterpret_cast<const float4*>(labels + blockFloatBase);
        float4* s4 = reinterpret_cast<float4*>(sh);
        #pragma unroll
        for (int k = 0; k < 8; ++k) {
            const int i = tid + k * 256;
            if (i < VEC4_PER_BLOCK) s4[i] = g[i];
        }
    }
    __syncthreads();

    float lv[CELL_STRIDE];
    {
        const float* myl = sh + tid * CELL_STRIDE;
        #pragma unroll
        for (int k = 0; k < 3; ++k) {           // box + obj (+pad)
            float2 t = *reinterpret_cast<const float2*>(myl + 2 * k);
            lv[2 * k] = t.x; lv[2 * k + 1] = t.y;
        }
        #pragma unroll
        for (int k = 5; k < 15; ++k) {          // classes
            float2 t = *reinterpret_cast<const float2*>(myl + 2 * k);
            lv[2 * k] = t.x; lv[2 * k + 1] = t.y;
        }
    }

    // ---- compute ----
    const int cell = blockIdx.x * CELLS_PER_BLOCK + tid;
    const int rem = cell % (SS * SS);
    const float gx = (float)(rem % SS);   // meshgrid 'xy': x = col index
    const float gy = (float)(rem / SS);   // y = row index

    const float obj = lv[4];
    const float lx = lv[0], ly = lv[1], lw = lv[2], lh = lv[3];
    const float l_cx = (gx + lx) / 7.0f;
    const float l_cy = (gy + ly) / 7.0f;
    const float l_minx = l_cx - lw * 0.5f, l_maxx = l_cx + lw * 0.5f;
    const float l_miny = l_cy - lh * 0.5f, l_maxy = l_cy + lh * 0.5f;
    const float area_l = lw * lh;

    float iou[2], box_err[2], conf[2];
    #pragma unroll
    for (int b = 0; b < 2; ++b) {
        const float px = pv[5 * b + 0], py = pv[5 * b + 1];
        const float pw = pv[5 * b + 2], ph = pv[5 * b + 3];
        conf[b] = pv[5 * b + 4];
        const float p_cx = (gx + px) / 7.0f;
        const float p_cy = (gy + py) / 7.0f;
        const float p_minx = p_cx - pw * 0.5f, p_maxx = p_cx + pw * 0.5f;
        const float p_miny = p_cy - ph * 0.5f, p_maxy = p_cy + ph * 0.5f;
        float iw = fminf(p_maxx, l_maxx) - fmaxf(p_minx, l_minx);
        float ih = fminf(p_maxy, l_maxy) - fmaxf(p_miny, l_miny);
        iw = fmaxf(iw, 0.0f); ih = fmaxf(ih, 0.0f);
        const float inter = iw * ih;
        const float uni = pw * ph + area_l - inter + 1e-10f;
        iou[b] = inter / uni;
        const float dx = px - lx, dy = py - ly;
        const float dw = sqrtf(pw) - sqrtf(lw);
        const float dh = sqrtf(ph) - sqrtf(lh);
        box_err[b] = (dx * dx + dy * dy) + (dw * dw + dh * dh);
    }

    // argmax tie-break: first max wins -> box 1 only if strictly greater
    const int r = (iou[1] > iou[0]) ? 1 : 0;
    const float cr = conf[r], cn = conf[1 - r];

    float loss = obj * (5.0f * box_err[r] + (cr - iou[r]) * (cr - iou[r]));
    // noobj: mask is (1-obj) on responsible box, 1 on the other
    loss += 0.5f * ((1.0f - obj) * cr * cr + cn * cn);

    float cls = 0.0f;
    #pragma unroll
    for (int k = 10; k < 30; ++k) {
        const float d = pv[k] - lv[k];
        cls += d * d;
    }
    loss += obj * cls;

    float acc = loss * inv_bs;

    // wave (64-lane) shuffle reduction
    #pragma unroll
    for (int off = 32; off > 0; off >>= 1)
        acc += __shfl_down(acc, off, 64);

    __shared__ float wsum[4];
    const int lane = tid & 63;
    const int wid  = tid >> 6;
    if (lane == 0) wsum[wid] = acc;
    __syncthreads();
    if (tid == 0) {
        atomicAdd(out, wsum[0] + wsum[1] + wsum[2] + wsum[3]);
    }
}

extern "C" void kernel_launch(void* const* d_in, const int* in_sizes, int n_in,
                              void* d_out, int out_size, void* d_ws, size_t ws_size,
                              hipStream_t stream) {
    const float* preds  = (const float*)d_in[0];
    const float* labels = (const float*)d_in[1];
    float* out = (float*)d_out;

    const int ncells = in_sizes[0] / CELL_STRIDE;        // 16384*49 = 802816
    const int bs     = ncells / (SS * SS);               // 16384
    const float inv_bs = 1.0f / (float)bs;

    yolo_zero_out<<<1, 64, 0, stream>>>(out);

    const int grid = ncells / CELLS_PER_BLOCK;           // 3136 (exact)
    yolo_loss_kernel<<<grid, 256, 0, stream>>>(preds, labels, out, inv_bs);
}

// Round 3
// 211.866 us; speedup vs baseline: 1.0484x; 1.0484x over previous
//
#include <hip/hip_runtime.h>

// YOLO-v1 loss forward, S=7, B=2, C=20, bs=16384.
// 193 MB in -> 4 B out; floor ~31 us @ 6.3 TB/s (less if L3-resident).
// R3: remove same-address atomicAdd serialization (prime suspect for the
// 86 us plateau across R1/R2): per-block partials -> d_ws, second kernel
// reduces. Grid-stride with 1280 blocks (5 resident/CU at 30 KB LDS).

#define SS 7
#define CELL_STRIDE 30          // 5*B + C floats per cell
#define CELLS_PER_BLOCK 256
#define FLOATS_PER_BLOCK (CELLS_PER_BLOCK * CELL_STRIDE)   // 7680
#define VEC4_PER_BLOCK (FLOATS_PER_BLOCK / 4)              // 1920
#define NBLOCKS 1280

__device__ __forceinline__ float yolo_cell_loss(const float* pv, const float* lv, int cell) {
    const int rem = cell % (SS * SS);
    const float gx = (float)(rem % SS);   // meshgrid 'xy': x = col
    const float gy = (float)(rem / SS);   // y = row

    const float obj = lv[4];
    const float lx = lv[0], ly = lv[1], lw = lv[2], lh = lv[3];
    const float l_cx = (gx + lx) / 7.0f;
    const float l_cy = (gy + ly) / 7.0f;
    const float l_minx = l_cx - lw * 0.5f, l_maxx = l_cx + lw * 0.5f;
    const float l_miny = l_cy - lh * 0.5f, l_maxy = l_cy + lh * 0.5f;
    const float area_l = lw * lh;

    float iou[2], box_err[2], conf[2];
    #pragma unroll
    for (int b = 0; b < 2; ++b) {
        const float px = pv[5 * b + 0], py = pv[5 * b + 1];
        const float pw = pv[5 * b + 2], ph = pv[5 * b + 3];
        conf[b] = pv[5 * b + 4];
        const float p_cx = (gx + px) / 7.0f;
        const float p_cy = (gy + py) / 7.0f;
        const float p_minx = p_cx - pw * 0.5f, p_maxx = p_cx + pw * 0.5f;
        const float p_miny = p_cy - ph * 0.5f, p_maxy = p_cy + ph * 0.5f;
        float iw = fminf(p_maxx, l_maxx) - fmaxf(p_minx, l_minx);
        float ih = fminf(p_maxy, l_maxy) - fmaxf(p_miny, l_miny);
        iw = fmaxf(iw, 0.0f); ih = fmaxf(ih, 0.0f);
        const float inter = iw * ih;
        const float uni = pw * ph + area_l - inter + 1e-10f;
        iou[b] = inter / uni;
        const float dx = px - lx, dy = py - ly;
        const float dw = sqrtf(pw) - sqrtf(lw);
        const float dh = sqrtf(ph) - sqrtf(lh);
        box_err[b] = (dx * dx + dy * dy) + (dw * dw + dh * dh);
    }

    // argmax tie-break: first max wins -> box 1 only if strictly greater
    const int r = (iou[1] > iou[0]) ? 1 : 0;
    const float cr = conf[r], cn = conf[1 - r];

    float loss = obj * (5.0f * box_err[r] + (cr - iou[r]) * (cr - iou[r]));
    loss += 0.5f * ((1.0f - obj) * cr * cr + cn * cn);

    float cls = 0.0f;
    #pragma unroll
    for (int k = 10; k < 30; ++k) {
        const float d = pv[k] - lv[k];
        cls += d * d;
    }
    loss += obj * cls;
    return loss;
}

__global__ __launch_bounds__(256) void yolo_loss_partial(
    const float* __restrict__ preds,
    const float* __restrict__ labels,
    float* __restrict__ partial,
    int nslabs, float inv_bs, int use_atomic)
{
    __shared__ float sh[FLOATS_PER_BLOCK];   // 30720 B -> 5 blocks/CU
    const int tid = threadIdx.x;
    float acc = 0.0f;

    for (int slab = blockIdx.x; slab < nslabs; slab += gridDim.x) {
        const size_t base = (size_t)slab * FLOATS_PER_BLOCK;

        // stage preds slab (coalesced float4)
        {
            const float4* g = reinterpret_cast<const float4*>(preds + base);
            float4* s4 = reinterpret_cast<float4*>(sh);
            #pragma unroll
            for (int k = 0; k < 8; ++k) {
                const int i = tid + k * 256;
                if (i < VEC4_PER_BLOCK) s4[i] = g[i];
            }
        }
        __syncthreads();
        float pv[CELL_STRIDE];
        {
            const float* myp = sh + tid * CELL_STRIDE;
            #pragma unroll
            for (int k = 0; k < 15; ++k) {
                float2 t = *reinterpret_cast<const float2*>(myp + 2 * k);
                pv[2 * k] = t.x; pv[2 * k + 1] = t.y;
            }
        }
        __syncthreads();

        // stage labels slab into same buffer
        {
            const float4* g = reinterpret_cast<const float4*>(labels + base);
            float4* s4 = reinterpret_cast<float4*>(sh);
            #pragma unroll
            for (int k = 0; k < 8; ++k) {
                const int i = tid + k * 256;
                if (i < VEC4_PER_BLOCK) s4[i] = g[i];
            }
        }
        __syncthreads();
        float lv[CELL_STRIDE];
        {
            const float* myl = sh + tid * CELL_STRIDE;
            #pragma unroll
            for (int k = 0; k < 3; ++k) {
                float2 t = *reinterpret_cast<const float2*>(myl + 2 * k);
                lv[2 * k] = t.x; lv[2 * k + 1] = t.y;
            }
            #pragma unroll
            for (int k = 5; k < 15; ++k) {
                float2 t = *reinterpret_cast<const float2*>(myl + 2 * k);
                lv[2 * k] = t.x; lv[2 * k + 1] = t.y;
            }
        }

        acc += yolo_cell_loss(pv, lv, slab * CELLS_PER_BLOCK + tid);
        __syncthreads();   // protect sh before next slab's staging
    }

    acc *= inv_bs;

    // wave (64-lane) shuffle reduction
    #pragma unroll
    for (int off = 32; off > 0; off >>= 1)
        acc += __shfl_down(acc, off, 64);

    __shared__ float wsum[4];
    const int lane = tid & 63;
    const int wid  = tid >> 6;
    if (lane == 0) wsum[wid] = acc;
    __syncthreads();
    if (tid == 0) {
        const float blocksum = wsum[0] + wsum[1] + wsum[2] + wsum[3];
        if (use_atomic) atomicAdd(partial, blocksum);        // fallback: partial==out
        else            partial[blockIdx.x] = blocksum;
    }
}

__global__ __launch_bounds__(256) void yolo_reduce(
    const float* __restrict__ partial, float* __restrict__ out, int n)
{
    float acc = 0.0f;
    for (int i = threadIdx.x; i < n; i += 256) acc += partial[i];
    #pragma unroll
    for (int off = 32; off > 0; off >>= 1)
        acc += __shfl_down(acc, off, 64);
    __shared__ float wsum[4];
    const int lane = threadIdx.x & 63;
    const int wid  = threadIdx.x >> 6;
    if (lane == 0) wsum[wid] = acc;
    __syncthreads();
    if (threadIdx.x == 0) out[0] = wsum[0] + wsum[1] + wsum[2] + wsum[3];
}

__global__ void yolo_zero_out(float* out) {
    if (threadIdx.x == 0) out[0] = 0.0f;
}

extern "C" void kernel_launch(void* const* d_in, const int* in_sizes, int n_in,
                              void* d_out, int out_size, void* d_ws, size_t ws_size,
                              hipStream_t stream) {
    const float* preds  = (const float*)d_in[0];
    const float* labels = (const float*)d_in[1];
    float* out = (float*)d_out;

    const int ncells = in_sizes[0] / CELL_STRIDE;        // 802816
    const int nslabs = ncells / CELLS_PER_BLOCK;         // 3136
    const int bs     = ncells / (SS * SS);               // 16384
    const float inv_bs = 1.0f / (float)bs;

    if (ws_size >= NBLOCKS * sizeof(float)) {
        float* partial = (float*)d_ws;
        yolo_loss_partial<<<NBLOCKS, 256, 0, stream>>>(preds, labels, partial,
                                                       nslabs, inv_bs, 0);
        yolo_reduce<<<1, 256, 0, stream>>>(partial, out, NBLOCKS);
    } else {
        // fallback: atomic accumulation directly into out
        yolo_zero_out<<<1, 64, 0, stream>>>(out);
        yolo_loss_partial<<<NBLOCKS, 256, 0, stream>>>(preds, labels, out,
                                                       nslabs, inv_bs, 1);
    }
}